// Round 7
// baseline (101.451 us; speedup 1.0000x reference)
//
#include <hip/hip_runtime.h>
#include <hip/hip_bf16.h>

// Single-head causal attention. B=4, T=2048, E=768, H=64.
// x[4,2048,768] f32; Wk,Wq,Wv [768,64] f32. Out [4,2048,64] f32.
// R15: SPLIT_KB 4->8 (MAX_SP 8->4). Halves the split-combine: po 9.2->4.7MB,
// writer blocks 560->288, reduce loop <=4 splits. attn critical chain grows
// to <=8 kb-iters (~2.8us), 320 active blocks (1.25/CU). Designed experiment:
// if combine-bound -> -3..-5us; if attn-parallelism-bound -> +1..+3us.
// Keeps R13's T14 async-STAGE (measured 101.2us best). proj/reduce structure
// unchanged.
// NOTE: dur_us includes ~44us harness reset (256MiB ws poison fill).

typedef __attribute__((ext_vector_type(8))) short short8;
typedef __attribute__((ext_vector_type(4))) float f32x4;

#define SPLIT_KB 8          // key-blocks (of 64) per split
#define MAX_SP 4            // ceil(32/8)

__device__ __forceinline__ unsigned short f2bf(float f) {
    union { float f; unsigned u; } v; v.f = f;
    unsigned r = v.u + 0x7fffu + ((v.u >> 16) & 1u);  // RNE
    return (unsigned short)(r >> 16);
}

// ---- projections, grid (256, 3): block = 32 rows x 64 cols of matrix my
// W f32 [768][64] transposed+bf16-converted during staging.
__global__ __launch_bounds__(256) void proj_kernel(const float* __restrict__ x,
                                                   const float* __restrict__ Wk,
                                                   const float* __restrict__ Wq,
                                                   const float* __restrict__ Wv,
                                                   unsigned short* __restrict__ qws,
                                                   unsigned short* __restrict__ kws,
                                                   unsigned short* __restrict__ vT) {
    __shared__ unsigned short xs[32 * 72];    // [row][k]
    __shared__ unsigned short wsm[64 * 72];   // [n][k] (transposed W chunk)
    const float CSCALE = 1.4426950408889634f / 27.712812921102035f;  // log2e/sqrt(768)
    int tid = threadIdx.x;
    int lane = tid & 63, wave = tid >> 6;
    int quad = lane >> 4, l16 = lane & 15;
    int row0 = blockIdx.x * 32;
    int my = blockIdx.y;                      // 0=q 1=k 2=v
    const float* W = (my == 0) ? Wq : (my == 1) ? Wk : Wv;

    int xrow = tid >> 3, xcb = (tid & 7) * 8;
    int wn = tid & 63, wk0 = (tid >> 6) * 16;

    f32x4 acc[2];
    acc[0] = (f32x4)(0.f); acc[1] = (f32x4)(0.f);

    for (int kc = 0; kc < 12; ++kc) {
        __syncthreads();
        {   // stage x 32x64 f32 -> bf16
            const float* src = x + (size_t)(row0 + xrow) * 768 + kc * 64 + xcb;
            float4 f0 = *(const float4*)(src);
            float4 f1 = *(const float4*)(src + 4);
            short8 pk;
            pk[0] = (short)f2bf(f0.x); pk[1] = (short)f2bf(f0.y);
            pk[2] = (short)f2bf(f0.z); pk[3] = (short)f2bf(f0.w);
            pk[4] = (short)f2bf(f1.x); pk[5] = (short)f2bf(f1.y);
            pk[6] = (short)f2bf(f1.z); pk[7] = (short)f2bf(f1.w);
            *(short8*)&xs[xrow * 72 + xcb] = pk;
        }
        {   // stage W chunk transposed: wsm[n][k] = W[kc*64+k][n]
            float wv[16];
            for (int i = 0; i < 16; ++i)
                wv[i] = W[(size_t)(kc * 64 + wk0 + i) * 64 + wn];
            if (my == 0)
                for (int i = 0; i < 16; ++i) wv[i] *= CSCALE;
            short8 p0, p1;
            for (int i = 0; i < 8; ++i) { p0[i] = (short)f2bf(wv[i]); p1[i] = (short)f2bf(wv[8 + i]); }
            *(short8*)&wsm[wn * 72 + wk0] = p0;
            *(short8*)&wsm[wn * 72 + wk0 + 8] = p1;
        }
        __syncthreads();
        for (int kh = 0; kh < 2; ++kh) {
            int kk = kh * 32 + quad * 8;
            short8 bfr = *(const short8*)&wsm[(wave * 16 + l16) * 72 + kk];
            for (int mt = 0; mt < 2; ++mt) {
                short8 a = *(const short8*)&xs[(mt * 16 + l16) * 72 + kk];
                acc[mt] = __builtin_amdgcn_mfma_f32_16x16x32_bf16(a, bfr, acc[mt], 0, 0, 0);
            }
        }
    }
    __syncthreads();
    int n = wave * 16 + l16;
    if (my != 2) {
        unsigned short* dst = (my == 0) ? qws : kws;
        for (int mt = 0; mt < 2; ++mt)
            for (int j = 0; j < 4; ++j) {
                int rloc = mt * 16 + quad * 4 + j;
                dst[(size_t)(row0 + rloc) * 64 + n] = f2bf(acc[mt][j]);
            }
    } else {
        for (int mt = 0; mt < 2; ++mt)
            for (int j = 0; j < 4; ++j) {
                int rloc = mt * 16 + quad * 4 + j;
                wsm[n * 40 + rloc] = f2bf(acc[mt][j]);
            }
        __syncthreads();
        int bidx = row0 >> 11, t0 = row0 & 2047;
        int c = tid >> 2, rb = (tid & 3) * 8;
        *(short8*)&vT[((size_t)(bidx * 64 + c)) * 2048 + t0 + rb] =
            *(const short8*)&wsm[c * 40 + rb];
    }
}

// ---- split-K flash attention (no-max softmax): grid (32,4,4), 256 thr
// 64-row Q tiles; T14 async-STAGE: next K/V tile loaded to regs during compute.
__global__ __launch_bounds__(256) void attn_split(const unsigned short* __restrict__ qws,
                                                  const unsigned short* __restrict__ kws,
                                                  const unsigned short* __restrict__ vT,
                                                  float* __restrict__ po,
                                                  float* __restrict__ pl,
                                                  float* __restrict__ out) {
    int bx = blockIdx.x, b = blockIdx.y, sp = blockIdx.z;
    int kbmax = bx + 1;                           // # key-blocks for this tile
    int nsp = (kbmax + SPLIT_KB - 1) / SPLIT_KB;
    if (sp >= nsp) return;
    int kb_lo = sp * SPLIT_KB;
    int kb_hi = min(kb_lo + SPLIT_KB, kbmax);

    __shared__ unsigned short qs[64 * 72];
    __shared__ unsigned short ks[64 * 72];
    __shared__ unsigned short vs[64 * 72];
    __shared__ unsigned short ps[4][16 * 72];
    int tid = threadIdx.x;
    int lane = tid & 63, wave = tid >> 6;
    int quad = lane >> 4, l16 = lane & 15;
    int q0 = bx * 64;
    size_t qbase = ((size_t)b * 2048 + q0) * 64;
    for (int i = 0; i < 2; ++i) {
        int e = tid + 256 * i;
        int r = e >> 3, hb = (e & 7) * 8;
        *(short8*)&qs[r * 72 + hb] = *(const short8*)&qws[qbase + r * 64 + hb];
    }
    __syncthreads();
    short8 aq[2];
    for (int kh = 0; kh < 2; ++kh)
        aq[kh] = *(const short8*)&qs[(wave * 16 + l16) * 72 + kh * 32 + quad * 8];

    f32x4 o_acc[4];
    for (int nt = 0; nt < 4; ++nt) o_acc[nt] = (f32x4)(0.f);
    float l_run[4];                 // per-lane partial row sums (order-free, m=0)
    int row_g[4];
    for (int j = 0; j < 4; ++j) {
        l_run[j] = 0.f;
        row_g[j] = q0 + wave * 16 + quad * 4 + j;
    }

    // T14 async-STAGE: K/V tile travels global->reg (early) -> LDS (late)
    short8 kreg[2], vreg[2];
    int sr[2], shb[2], sh[2], skb[2];
    for (int i = 0; i < 2; ++i) {
        int e = tid + 256 * i;
        sr[i] = e >> 3; shb[i] = (e & 7) * 8;     // K staging coords
        sh[i] = e >> 3; skb[i] = (e & 7) * 8;     // V staging coords
    }
    {
        size_t kvbase = ((size_t)b * 2048 + kb_lo * 64) * 64;
        for (int i = 0; i < 2; ++i)
            kreg[i] = *(const short8*)&kws[kvbase + sr[i] * 64 + shb[i]];
        for (int i = 0; i < 2; ++i)
            vreg[i] = *(const short8*)&vT[((size_t)b * 64 + sh[i]) * 2048 + kb_lo * 64 + skb[i]];
    }

    for (int kb = kb_lo; kb < kb_hi; ++kb) {
        __syncthreads();      // previous tile's LDS reads complete
        for (int i = 0; i < 2; ++i)
            *(short8*)&ks[sr[i] * 72 + shb[i]] = kreg[i];
        for (int i = 0; i < 2; ++i)
            *(short8*)&vs[sh[i] * 72 + skb[i]] = vreg[i];
        __syncthreads();      // tile kb visible
        if (kb + 1 < kb_hi) { // issue next tile's loads; latency hides under compute
            size_t kvbase = ((size_t)b * 2048 + (kb + 1) * 64) * 64;
            for (int i = 0; i < 2; ++i)
                kreg[i] = *(const short8*)&kws[kvbase + sr[i] * 64 + shb[i]];
            for (int i = 0; i < 2; ++i)
                vreg[i] = *(const short8*)&vT[((size_t)b * 64 + sh[i]) * 2048 + (kb + 1) * 64 + skb[i]];
        }
        f32x4 s[4];
        for (int nt = 0; nt < 4; ++nt) s[nt] = (f32x4)(0.f);
        for (int kh = 0; kh < 2; ++kh)
            for (int nt = 0; nt < 4; ++nt) {
                short8 bk = *(const short8*)&ks[(nt * 16 + l16) * 72 + kh * 32 + quad * 8];
                s[nt] = __builtin_amdgcn_mfma_f32_16x16x32_bf16(aq[kh], bk, s[nt], 0, 0, 0);
            }
        if (kb == kbmax - 1) {                    // diagonal block only
            for (int nt = 0; nt < 4; ++nt) {
                int key = kb * 64 + nt * 16 + l16;
                for (int j = 0; j < 4; ++j)
                    if (key > row_g[j]) s[nt][j] = -1e30f;   // exp2 -> 0
            }
        }
        // no-max softmax: p = exp2(s); l accumulates per-lane (reduced at end)
        for (int nt = 0; nt < 4; ++nt)
            for (int j = 0; j < 4; ++j) {
                float p = exp2f(s[nt][j]);
                l_run[j] += p;
                ps[wave][(quad * 4 + j) * 72 + nt * 16 + l16] = f2bf(p);
            }
        for (int kh = 0; kh < 2; ++kh) {
            short8 ap = *(const short8*)&ps[wave][l16 * 72 + kh * 32 + quad * 8];
            for (int nt = 0; nt < 4; ++nt) {
                short8 bv = *(const short8*)&vs[(nt * 16 + l16) * 72 + kh * 32 + quad * 8];
                o_acc[nt] = __builtin_amdgcn_mfma_f32_16x16x32_bf16(ap, bv, o_acc[nt], 0, 0, 0);
            }
        }
    }
    // deferred row-sum: reduce l_run across the 16 lanes of each quad-group
    for (int off = 1; off < 16; off <<= 1)
        for (int j = 0; j < 4; ++j)
            l_run[j] += __shfl_xor(l_run[j], off, 16);

    if (nsp == 1) {       // single split: write normalized output directly
        for (int nt = 0; nt < 4; ++nt)
            for (int j = 0; j < 4; ++j)
                out[((size_t)b * 2048 + row_g[j]) * 64 + nt * 16 + l16] =
                    o_acc[nt][j] / l_run[j];
        return;
    }
    int sbase = ((b * 32 + bx) * MAX_SP + sp) * 64;   // row-slot base
    for (int nt = 0; nt < 4; ++nt)
        for (int j = 0; j < 4; ++j) {
            int r = wave * 16 + quad * 4 + j;
            po[(size_t)(sbase + r) * 64 + nt * 16 + l16] = o_acc[nt][j];
        }
    if (l16 == 0) {
        for (int j = 0; j < 4; ++j) {
            int r = wave * 16 + quad * 4 + j;
            pl[sbase + r] = l_run[j];
        }
    }
}

// ---- combine splits: plain sums (no max weighting); 1 wave per output row
__global__ __launch_bounds__(256) void reduce_kernel(const float* __restrict__ po,
                                                     const float* __restrict__ pl,
                                                     float* __restrict__ out) {
    int tid = threadIdx.x;
    int lane = tid & 63, wave = tid >> 6;
    int g = blockIdx.x * 4 + wave;        // row id [0, 8192)
    int b = g >> 11, t = g & 2047;
    int bx = t >> 6, r = t & 63;
    int kbmax = bx + 1;
    int nsp = (kbmax + SPLIT_KB - 1) / SPLIT_KB;
    if (nsp == 1) return;                 // written by attn_split directly
    int base = ((b * 32 + bx) * MAX_SP) * 64 + r;
    float acc = 0.f, lsum = 0.f;
    for (int sp = 0; sp < nsp; ++sp) {
        acc += po[(size_t)(base + sp * 64) * 64 + lane];
        lsum += pl[base + sp * 64];
    }
    out[(size_t)g * 64 + lane] = acc / lsum;
}

extern "C" void kernel_launch(void* const* d_in, const int* in_sizes, int n_in,
                              void* d_out, int out_size, void* d_ws, size_t ws_size,
                              hipStream_t stream) {
    const float* x  = (const float*)d_in[0];
    const float* Wk = (const float*)d_in[1];
    const float* Wq = (const float*)d_in[2];
    const float* Wv = (const float*)d_in[3];
    float* out = (float*)d_out;
    // ws layout (bytes):
    //   qws @ 0         (1 MB)
    //   kws @ 1048576   (1 MB)
    //   vT  @ 2097152   (1 MB)
    //   po  @ 3145728   (8.39 MB: 4b * 32bx * 4sp * 64 rows * 64 h * f32)
    //   pl  @ 11534336  (131072)   total ~11.7 MB
    char* w = (char*)d_ws;
    unsigned short* qws = (unsigned short*)w;
    unsigned short* kws = (unsigned short*)(w + 1048576);
    unsigned short* vT  = (unsigned short*)(w + 2097152);
    float* po = (float*)(w + 3145728);
    float* pl = (float*)(w + 11534336);
    proj_kernel<<<dim3(256, 3), 256, 0, stream>>>(x, Wk, Wq, Wv, qws, kws, vT);
    attn_split<<<dim3(32, 4, MAX_SP), 256, 0, stream>>>(qws, kws, vT, po, pl, out);
    reduce_kernel<<<2048, 256, 0, stream>>>(po, pl, out);
}

// Round 8
// 98.593 us; speedup vs baseline: 1.0290x; 1.0290x over previous
//
#include <hip/hip_runtime.h>
#include <hip/hip_bf16.h>

// Single-head causal attention. B=4, T=2048, E=768, H=64.
// x[4,2048,768] f32; Wk,Wq,Wv [768,64] f32. Out [4,2048,64] f32.
// R16: base = R13 (measured best 101.2us: 64-row Q-tiles + T14 async-STAGE,
// SPLIT_KB=4). Single change: all bf16 conversions go through
// __float2bfloat16 (HW v_cvt_pk_bf16_f32 path, RNE) instead of the manual
// bit-twiddle RNE (~4 VALU ops/elem the compiler can't fuse). Conversion
// volume: proj 24/thread/iter, attn softmax 16/thread/iter on the QK^T->PV
// critical path. Predicted -2..-4us. R15's SPLIT_KB=8 was neutral (101.5);
// reverted for clean attribution.
// NOTE: dur_us includes ~44us harness reset (256MiB ws poison fill).

typedef __attribute__((ext_vector_type(8))) short short8;
typedef __attribute__((ext_vector_type(4))) float f32x4;

#define SPLIT_KB 4          // key-blocks (of 64) per split
#define MAX_SP 8            // ceil(32/4)

__device__ __forceinline__ unsigned short f2bf(float f) {
    union { __hip_bfloat16 h; unsigned short u; } c;
    c.h = __float2bfloat16(f);      // RNE; lowers to v_cvt_pk_bf16_f32 pairs
    return c.u;
}

// ---- projections, grid (256, 3): block = 32 rows x 64 cols of matrix my
// W f32 [768][64] transposed+bf16-converted during staging.
__global__ __launch_bounds__(256) void proj_kernel(const float* __restrict__ x,
                                                   const float* __restrict__ Wk,
                                                   const float* __restrict__ Wq,
                                                   const float* __restrict__ Wv,
                                                   unsigned short* __restrict__ qws,
                                                   unsigned short* __restrict__ kws,
                                                   unsigned short* __restrict__ vT) {
    __shared__ unsigned short xs[32 * 72];    // [row][k]
    __shared__ unsigned short wsm[64 * 72];   // [n][k] (transposed W chunk)
    const float CSCALE = 1.4426950408889634f / 27.712812921102035f;  // log2e/sqrt(768)
    int tid = threadIdx.x;
    int lane = tid & 63, wave = tid >> 6;
    int quad = lane >> 4, l16 = lane & 15;
    int row0 = blockIdx.x * 32;
    int my = blockIdx.y;                      // 0=q 1=k 2=v
    const float* W = (my == 0) ? Wq : (my == 1) ? Wk : Wv;

    int xrow = tid >> 3, xcb = (tid & 7) * 8;
    int wn = tid & 63, wk0 = (tid >> 6) * 16;

    f32x4 acc[2];
    acc[0] = (f32x4)(0.f); acc[1] = (f32x4)(0.f);

    for (int kc = 0; kc < 12; ++kc) {
        __syncthreads();
        {   // stage x 32x64 f32 -> bf16
            const float* src = x + (size_t)(row0 + xrow) * 768 + kc * 64 + xcb;
            float4 f0 = *(const float4*)(src);
            float4 f1 = *(const float4*)(src + 4);
            short8 pk;
            pk[0] = (short)f2bf(f0.x); pk[1] = (short)f2bf(f0.y);
            pk[2] = (short)f2bf(f0.z); pk[3] = (short)f2bf(f0.w);
            pk[4] = (short)f2bf(f1.x); pk[5] = (short)f2bf(f1.y);
            pk[6] = (short)f2bf(f1.z); pk[7] = (short)f2bf(f1.w);
            *(short8*)&xs[xrow * 72 + xcb] = pk;
        }
        {   // stage W chunk transposed: wsm[n][k] = W[kc*64+k][n]
            float wv[16];
            for (int i = 0; i < 16; ++i)
                wv[i] = W[(size_t)(kc * 64 + wk0 + i) * 64 + wn];
            if (my == 0)
                for (int i = 0; i < 16; ++i) wv[i] *= CSCALE;
            short8 p0, p1;
            for (int i = 0; i < 8; ++i) { p0[i] = (short)f2bf(wv[i]); p1[i] = (short)f2bf(wv[8 + i]); }
            *(short8*)&wsm[wn * 72 + wk0] = p0;
            *(short8*)&wsm[wn * 72 + wk0 + 8] = p1;
        }
        __syncthreads();
        for (int kh = 0; kh < 2; ++kh) {
            int kk = kh * 32 + quad * 8;
            short8 bfr = *(const short8*)&wsm[(wave * 16 + l16) * 72 + kk];
            for (int mt = 0; mt < 2; ++mt) {
                short8 a = *(const short8*)&xs[(mt * 16 + l16) * 72 + kk];
                acc[mt] = __builtin_amdgcn_mfma_f32_16x16x32_bf16(a, bfr, acc[mt], 0, 0, 0);
            }
        }
    }
    __syncthreads();
    int n = wave * 16 + l16;
    if (my != 2) {
        unsigned short* dst = (my == 0) ? qws : kws;
        for (int mt = 0; mt < 2; ++mt)
            for (int j = 0; j < 4; ++j) {
                int rloc = mt * 16 + quad * 4 + j;
                dst[(size_t)(row0 + rloc) * 64 + n] = f2bf(acc[mt][j]);
            }
    } else {
        for (int mt = 0; mt < 2; ++mt)
            for (int j = 0; j < 4; ++j) {
                int rloc = mt * 16 + quad * 4 + j;
                wsm[n * 40 + rloc] = f2bf(acc[mt][j]);
            }
        __syncthreads();
        int bidx = row0 >> 11, t0 = row0 & 2047;
        int c = tid >> 2, rb = (tid & 3) * 8;
        *(short8*)&vT[((size_t)(bidx * 64 + c)) * 2048 + t0 + rb] =
            *(const short8*)&wsm[c * 40 + rb];
    }
}

// ---- split-K flash attention (no-max softmax): grid (32,4,8), 256 thr
// 64-row Q tiles; T14 async-STAGE: next K/V tile loaded to regs during compute.
__global__ __launch_bounds__(256) void attn_split(const unsigned short* __restrict__ qws,
                                                  const unsigned short* __restrict__ kws,
                                                  const unsigned short* __restrict__ vT,
                                                  float* __restrict__ po,
                                                  float* __restrict__ pl,
                                                  float* __restrict__ out) {
    int bx = blockIdx.x, b = blockIdx.y, sp = blockIdx.z;
    int kbmax = bx + 1;                           // # key-blocks for this tile
    int nsp = (kbmax + SPLIT_KB - 1) / SPLIT_KB;
    if (sp >= nsp) return;
    int kb_lo = sp * SPLIT_KB;
    int kb_hi = min(kb_lo + SPLIT_KB, kbmax);

    __shared__ unsigned short qs[64 * 72];
    __shared__ unsigned short ks[64 * 72];
    __shared__ unsigned short vs[64 * 72];
    __shared__ unsigned short ps[4][16 * 72];
    int tid = threadIdx.x;
    int lane = tid & 63, wave = tid >> 6;
    int quad = lane >> 4, l16 = lane & 15;
    int q0 = bx * 64;
    size_t qbase = ((size_t)b * 2048 + q0) * 64;
    for (int i = 0; i < 2; ++i) {
        int e = tid + 256 * i;
        int r = e >> 3, hb = (e & 7) * 8;
        *(short8*)&qs[r * 72 + hb] = *(const short8*)&qws[qbase + r * 64 + hb];
    }
    __syncthreads();
    short8 aq[2];
    for (int kh = 0; kh < 2; ++kh)
        aq[kh] = *(const short8*)&qs[(wave * 16 + l16) * 72 + kh * 32 + quad * 8];

    f32x4 o_acc[4];
    for (int nt = 0; nt < 4; ++nt) o_acc[nt] = (f32x4)(0.f);
    float l_run[4];                 // per-lane partial row sums (order-free, m=0)
    int row_g[4];
    for (int j = 0; j < 4; ++j) {
        l_run[j] = 0.f;
        row_g[j] = q0 + wave * 16 + quad * 4 + j;
    }

    // T14 async-STAGE: K/V tile travels global->reg (early) -> LDS (late)
    short8 kreg[2], vreg[2];
    int sr[2], shb[2], sh[2], skb[2];
    for (int i = 0; i < 2; ++i) {
        int e = tid + 256 * i;
        sr[i] = e >> 3; shb[i] = (e & 7) * 8;     // K staging coords
        sh[i] = e >> 3; skb[i] = (e & 7) * 8;     // V staging coords
    }
    {
        size_t kvbase = ((size_t)b * 2048 + kb_lo * 64) * 64;
        for (int i = 0; i < 2; ++i)
            kreg[i] = *(const short8*)&kws[kvbase + sr[i] * 64 + shb[i]];
        for (int i = 0; i < 2; ++i)
            vreg[i] = *(const short8*)&vT[((size_t)b * 64 + sh[i]) * 2048 + kb_lo * 64 + skb[i]];
    }

    for (int kb = kb_lo; kb < kb_hi; ++kb) {
        __syncthreads();      // previous tile's LDS reads complete
        for (int i = 0; i < 2; ++i)
            *(short8*)&ks[sr[i] * 72 + shb[i]] = kreg[i];
        for (int i = 0; i < 2; ++i)
            *(short8*)&vs[sh[i] * 72 + skb[i]] = vreg[i];
        __syncthreads();      // tile kb visible
        if (kb + 1 < kb_hi) { // issue next tile's loads; latency hides under compute
            size_t kvbase = ((size_t)b * 2048 + (kb + 1) * 64) * 64;
            for (int i = 0; i < 2; ++i)
                kreg[i] = *(const short8*)&kws[kvbase + sr[i] * 64 + shb[i]];
            for (int i = 0; i < 2; ++i)
                vreg[i] = *(const short8*)&vT[((size_t)b * 64 + sh[i]) * 2048 + (kb + 1) * 64 + skb[i]];
        }
        f32x4 s[4];
        for (int nt = 0; nt < 4; ++nt) s[nt] = (f32x4)(0.f);
        for (int kh = 0; kh < 2; ++kh)
            for (int nt = 0; nt < 4; ++nt) {
                short8 bk = *(const short8*)&ks[(nt * 16 + l16) * 72 + kh * 32 + quad * 8];
                s[nt] = __builtin_amdgcn_mfma_f32_16x16x32_bf16(aq[kh], bk, s[nt], 0, 0, 0);
            }
        if (kb == kbmax - 1) {                    // diagonal block only
            for (int nt = 0; nt < 4; ++nt) {
                int key = kb * 64 + nt * 16 + l16;
                for (int j = 0; j < 4; ++j)
                    if (key > row_g[j]) s[nt][j] = -1e30f;   // exp2 -> 0
            }
        }
        // no-max softmax: p = exp2(s); l accumulates per-lane (reduced at end)
        for (int nt = 0; nt < 4; ++nt)
            for (int j = 0; j < 4; ++j) {
                float p = exp2f(s[nt][j]);
                l_run[j] += p;
                ps[wave][(quad * 4 + j) * 72 + nt * 16 + l16] = f2bf(p);
            }
        for (int kh = 0; kh < 2; ++kh) {
            short8 ap = *(const short8*)&ps[wave][l16 * 72 + kh * 32 + quad * 8];
            for (int nt = 0; nt < 4; ++nt) {
                short8 bv = *(const short8*)&vs[(nt * 16 + l16) * 72 + kh * 32 + quad * 8];
                o_acc[nt] = __builtin_amdgcn_mfma_f32_16x16x32_bf16(ap, bv, o_acc[nt], 0, 0, 0);
            }
        }
    }
    // deferred row-sum: reduce l_run across the 16 lanes of each quad-group
    for (int off = 1; off < 16; off <<= 1)
        for (int j = 0; j < 4; ++j)
            l_run[j] += __shfl_xor(l_run[j], off, 16);

    if (nsp == 1) {       // single split: write normalized output directly
        for (int nt = 0; nt < 4; ++nt)
            for (int j = 0; j < 4; ++j)
                out[((size_t)b * 2048 + row_g[j]) * 64 + nt * 16 + l16] =
                    o_acc[nt][j] / l_run[j];
        return;
    }
    int sbase = ((b * 32 + bx) * MAX_SP + sp) * 64;   // row-slot base
    for (int nt = 0; nt < 4; ++nt)
        for (int j = 0; j < 4; ++j) {
            int r = wave * 16 + quad * 4 + j;
            po[(size_t)(sbase + r) * 64 + nt * 16 + l16] = o_acc[nt][j];
        }
    if (l16 == 0) {
        for (int j = 0; j < 4; ++j) {
            int r = wave * 16 + quad * 4 + j;
            pl[sbase + r] = l_run[j];
        }
    }
}

// ---- combine splits: plain sums (no max weighting); 1 wave per output row
__global__ __launch_bounds__(256) void reduce_kernel(const float* __restrict__ po,
                                                     const float* __restrict__ pl,
                                                     float* __restrict__ out) {
    int tid = threadIdx.x;
    int lane = tid & 63, wave = tid >> 6;
    int g = blockIdx.x * 4 + wave;        // row id [0, 8192)
    int b = g >> 11, t = g & 2047;
    int bx = t >> 6, r = t & 63;
    int kbmax = bx + 1;
    int nsp = (kbmax + SPLIT_KB - 1) / SPLIT_KB;
    if (nsp == 1) return;                 // written by attn_split directly
    int base = ((b * 32 + bx) * MAX_SP) * 64 + r;
    float acc = 0.f, lsum = 0.f;
    for (int sp = 0; sp < nsp; ++sp) {
        acc += po[(size_t)(base + sp * 64) * 64 + lane];
        lsum += pl[base + sp * 64];
    }
    out[(size_t)g * 64 + lane] = acc / lsum;
}

extern "C" void kernel_launch(void* const* d_in, const int* in_sizes, int n_in,
                              void* d_out, int out_size, void* d_ws, size_t ws_size,
                              hipStream_t stream) {
    const float* x  = (const float*)d_in[0];
    const float* Wk = (const float*)d_in[1];
    const float* Wq = (const float*)d_in[2];
    const float* Wv = (const float*)d_in[3];
    float* out = (float*)d_out;
    // ws layout (bytes):
    //   qws @ 0         (1 MB)
    //   kws @ 1048576   (1 MB)
    //   vT  @ 2097152   (1 MB)
    //   po  @ 3145728   (16.78 MB: 4b * 32bx * 8sp * 64 rows * 64 h * f32)
    //   pl  @ 19922944  (262144)   total ~20.2 MB
    char* w = (char*)d_ws;
    unsigned short* qws = (unsigned short*)w;
    unsigned short* kws = (unsigned short*)(w + 1048576);
    unsigned short* vT  = (unsigned short*)(w + 2097152);
    float* po = (float*)(w + 3145728);
    float* pl = (float*)(w + 19922944);
    proj_kernel<<<dim3(256, 3), 256, 0, stream>>>(x, Wk, Wq, Wv, qws, kws, vT);
    attn_split<<<dim3(32, 4, MAX_SP), 256, 0, stream>>>(qws, kws, vT, po, pl, out);
    reduce_kernel<<<2048, 256, 0, stream>>>(po, pl, out);
}